// Round 13
// baseline (235.580 us; speedup 1.0000x reference)
//
#include <hip/hip_runtime.h>
#include <hip/hip_bf16.h>
#include <math.h>

#define NEG_SLOPE 0.2f
#define BN_EPS 1e-5f
#define ELLW 80          // ELL row width; deg = Poisson(32)+1, max over 20k nodes ~57; P(>80)~4e-13
#define SCLAMP 60.0f     // exp-arg clamp: scores analytically << 60; inf-guard only
#define LDP 68           // gemm LDS row stride in elements (136B)
#define NPOOL 16         // pool contention-splitting buckets

typedef __attribute__((ext_vector_type(8))) short bf16x8;
typedef __attribute__((ext_vector_type(4))) float f32x4;
typedef __attribute__((ext_vector_type(4))) unsigned u32x4;

__device__ __forceinline__ void atomAddF(float* p, float v) { unsafeAtomicAdd(p, v); }
__device__ __forceinline__ float bf_lo(unsigned u) { return __uint_as_float(u << 16); }
__device__ __forceinline__ float bf_hi(unsigned u) { return __uint_as_float(u & 0xffff0000u); }
__device__ __forceinline__ float lk(float x) { return x > 0.f ? x : NEG_SLOPE * x; }
__device__ __forceinline__ float eexp(float x) { return __expf(fminf(x, SCLAMP)); }
__device__ __forceinline__ unsigned packbf(float lo, float hi) {
    return (unsigned)__bfloat16_as_ushort(__float2bfloat16(lo)) |
           ((unsigned)__bfloat16_as_ushort(__float2bfloat16(hi)) << 16);
}

// ---- prep: zero scratch + cast x -> bf16 + transpose W1/W2 -> bf16 -------------
__global__ __launch_bounds__(256) void prep_kernel(const float* __restrict__ x,
                                                   const float* __restrict__ W1,
                                                   const float* __restrict__ W2,
                                                   __hip_bfloat16* __restrict__ xbf,
                                                   __hip_bfloat16* __restrict__ WT1,
                                                   __hip_bfloat16* __restrict__ WT2,
                                                   int* __restrict__ zb, int zwords,
                                                   int n4) {
    int i = blockIdx.x * blockDim.x + threadIdx.x;
    if (i < n4) {
        float4 v = ((const float4*)x)[i];
        ushort4 st;
        st.x = __bfloat16_as_ushort(__float2bfloat16(v.x));
        st.y = __bfloat16_as_ushort(__float2bfloat16(v.y));
        st.z = __bfloat16_as_ushort(__float2bfloat16(v.z));
        st.w = __bfloat16_as_ushort(__float2bfloat16(v.w));
        *(ushort4*)(xbf + (size_t)i * 4) = st;
        return;
    }
    int j = i - n4;
    if (j < 128 * 256) {          // W1 [128,256] -> WT1 [256,128]
        int k = j >> 8, n = j & 255;
        WT1[(size_t)n * 128 + k] = __float2bfloat16(W1[j]);
        return;
    }
    j -= 128 * 256;
    if (j < 256 * 128) {          // W2 [256,128] -> WT2 [128,256]
        int k = j >> 7, n = j & 127;
        WT2[(size_t)n * 256 + k] = __float2bfloat16(W2[j]);
        return;
    }
    j -= 256 * 128;
    if (j < zwords) zb[j] = 0;
}

// ------ MFMA GEMM body, LDS-staged, row-major C + score epilogue ------
// Cached C stores (R12 A/B: NT 2B stores bypass L2 write-combining, +9MB WRITE).
__device__ __forceinline__ void gemm_body(const __hip_bfloat16* __restrict__ A,
                                          const __hip_bfloat16* __restrict__ BT,
                                          __hip_bfloat16* __restrict__ C,
                                          const float* __restrict__ asrc,
                                          const float* __restrict__ adst,
                                          float* __restrict__ ssrc,
                                          float* __restrict__ sdst,
                                          int M, int N, int K, int heads,
                                          int bx, int by) {
    __shared__ __hip_bfloat16 As[64 * LDP];
    __shared__ __hip_bfloat16 Bs[64 * LDP];
    const int tid = threadIdx.x;
    const int w = tid >> 6;
    const int lane = tid & 63;
    const int q = lane >> 4;
    const int r16 = lane & 15;
    const int bm = by * 64;
    const int bn = bx * 64;
    const int lrow = tid >> 3;
    const int lseg = tid & 7;
    f32x4 acc[4] = {};

    for (int k0 = 0; k0 < K; k0 += 64) {
#pragma unroll
        for (int half = 0; half < 2; ++half) {
            int row = lrow + half * 32;
            int ga = min(bm + row, M - 1);
            *(bf16x8*)(&As[row * LDP + lseg * 8]) =
                *(const bf16x8*)(A + (size_t)ga * K + k0 + lseg * 8);
            *(bf16x8*)(&Bs[row * LDP + lseg * 8]) =
                *(const bf16x8*)(BT + (size_t)(bn + row) * K + k0 + lseg * 8);
        }
        __syncthreads();
#pragma unroll
        for (int kk = 0; kk < 64; kk += 32) {
            bf16x8 a = *(const bf16x8*)(&As[(w * 16 + r16) * LDP + kk + q * 8]);
#pragma unroll
            for (int t = 0; t < 4; ++t) {
                bf16x8 b = *(const bf16x8*)(&Bs[(t * 16 + r16) * LDP + kk + q * 8]);
                acc[t] = __builtin_amdgcn_mfma_f32_16x16x32_bf16(a, b, acc[t], 0, 0, 0);
            }
        }
        __syncthreads();
    }
#pragma unroll
    for (int t = 0; t < 4; ++t)
#pragma unroll
        for (int r = 0; r < 4; ++r) {
            int row = bm + w * 16 + q * 4 + r;
            if (row < M)
                C[(size_t)row * N + bn + t * 16 + r16] = __float2bfloat16(acc[t][r]);
        }
    if (heads) {
        const int h = (heads == 4) ? bx : 0;
        float asv[4], adv[4];
#pragma unroll
        for (int t = 0; t < 4; ++t) {
            int col = bn + t * 16 + r16;
            asv[t] = asrc[col]; adv[t] = adst[col];
        }
#pragma unroll
        for (int r = 0; r < 4; ++r) {
            int row = bm + w * 16 + q * 4 + r;
            float ss = 0.f, sd = 0.f;
#pragma unroll
            for (int t = 0; t < 4; ++t) { ss += acc[t][r] * asv[t]; sd += acc[t][r] * adv[t]; }
#pragma unroll
            for (int mask = 1; mask <= 8; mask <<= 1) {
                ss += __shfl_xor(ss, mask);
                sd += __shfl_xor(sd, mask);
            }
            if (r16 == 0 && row < M) {
                atomAddF(&ssrc[(size_t)row * heads + h], ss);
                atomAddF(&sdst[(size_t)row * heads + h], sd);
            }
        }
    }
}

// ---- merged dispatch: blocks [0,nbg) do gemm1, the rest do the ELL scatter -----
__global__ __launch_bounds__(256) void sg1_kernel(const __hip_bfloat16* __restrict__ A,
                                                  const __hip_bfloat16* __restrict__ BT,
                                                  __hip_bfloat16* __restrict__ C,
                                                  const float* __restrict__ asrc,
                                                  const float* __restrict__ adst,
                                                  float* __restrict__ ssrc,
                                                  float* __restrict__ sdst,
                                                  int M, int nbg,
                                                  const int* __restrict__ src,
                                                  const int* __restrict__ dst,
                                                  int* __restrict__ cnt,
                                                  unsigned short* __restrict__ ell,
                                                  int N, int E, int Etot) {
    const int gb = blockIdx.x;
    if (gb < nbg) {
        gemm_body(A, BT, C, asrc, adst, ssrc, sdst, M, 256, 128, 4, gb & 3, gb >> 2);
        return;
    }
    // ---- scatter, XCD-partitioned by dst chunk (absolute blockIdx -> XCD) ----
    const int xcd = gb & 7;
    const int sb = gb - nbg;
    const int slice = sb >> 3;
    const int nslices = (gridDim.x - nbg) >> 3;
    const int d0 = (int)((long)xcd * N / 8);
    const int d1 = (int)((long)(xcd + 1) * N / 8);
    for (int e = slice * 256 + threadIdx.x; e < Etot; e += nslices * 256) {
        int d = (e < E) ? dst[e] : e - E;
        if (d < d0 || d >= d1) continue;
        int s = (e < E) ? src[e] : d;
        int pos = atomicAdd(cnt + d, 1);
        if (pos < ELLW) ell[(size_t)d * ELLW + pos] = (unsigned short)s;
    }
}

// ---- standalone gemm (layer 2) ----
__global__ __launch_bounds__(256) void gemm_score_kernel(const __hip_bfloat16* __restrict__ A,
                                                         const __hip_bfloat16* __restrict__ BT,
                                                         __hip_bfloat16* __restrict__ C,
                                                         const float* __restrict__ asrc,
                                                         const float* __restrict__ adst,
                                                         float* __restrict__ ssrc,
                                                         float* __restrict__ sdst,
                                                         int M, int N, int K, int heads) {
    gemm_body(A, BT, C, asrc, adst, ssrc, sdst, M, N, K, heads, blockIdx.x, blockIdx.y);
}

// ---------------- Layer 1 fused (v2, 8-deep — empirical best) -------------------
__global__ __launch_bounds__(256) void fused1_kernel(const unsigned short* __restrict__ ell,
                                                     const int* __restrict__ cnt,
                                                     const float* __restrict__ ssrc,
                                                     const float* __restrict__ sdst,
                                                     const __hip_bfloat16* __restrict__ h1,
                                                     const float* __restrict__ b,
                                                     const float* __restrict__ g,
                                                     const float* __restrict__ be,
                                                     const float* __restrict__ rm,
                                                     const float* __restrict__ rv,
                                                     __hip_bfloat16* __restrict__ out1,
                                                     int N) {
    __shared__ float sex[4][ELLW * 4];       // per-edge exp weights (4 heads)
    __shared__ unsigned soff[4][ELLW];       // per-edge h1 row byte offset (s*512)
    const int w = threadIdx.x >> 6;
    const int lane = threadIdx.x & 63;
    const int n = blockIdx.x * 4 + w;
    if (n >= N) return;
    const int degn = min(cnt[n], ELLW);
    const unsigned short* __restrict__ row = ell + (size_t)n * ELLW;
    const float4 sd4 = *(const float4*)(sdst + (size_t)n * 4);

    float4 d4 = {0.f, 0.f, 0.f, 0.f};
    for (int i = lane; i < degn; i += 64) {
        int s = row[i];
        float4 sc = *(const float4*)(ssrc + (size_t)s * 4);
        float4 e4;
        e4.x = eexp(lk(sc.x + sd4.x)); e4.y = eexp(lk(sc.y + sd4.y));
        e4.z = eexp(lk(sc.z + sd4.z)); e4.w = eexp(lk(sc.w + sd4.w));
        *(float4*)(&sex[w][i * 4]) = e4;
        soff[w][i] = (unsigned)s << 9;
        d4.x += e4.x; d4.y += e4.y; d4.z += e4.z; d4.w += e4.w;
    }
    if (lane == 0 && (degn & 1)) {           // pad odd degree with a zero edge
        float4 z = {0.f, 0.f, 0.f, 0.f};
        *(float4*)(&sex[w][degn * 4]) = z;
        soff[w][degn] = 0;
    }
#pragma unroll
    for (int o = 32; o; o >>= 1) {
        d4.x += __shfl_xor(d4.x, o); d4.y += __shfl_xor(d4.y, o);
        d4.z += __shfl_xor(d4.z, o); d4.w += __shfl_xor(d4.w, o);
    }

    const int half = lane >> 5;              // which edge of the pair
    const int l32 = lane & 31;
    const int ch = l32 * 8;                  // 8 channels per lane
    const int h = l32 >> 3;                  // head = ch/64
    const unsigned choff = (unsigned)(l32 * 16);  // ch*2 bytes
    const float denh = h == 0 ? d4.x : h == 1 ? d4.y : h == 2 ? d4.z : d4.w;
    const float rden = 1.f / (denh + 1e-16f);
    const unsigned char* __restrict__ hb = (const unsigned char*)h1;
    const int degp = (degn + 1) & ~1;

    f32x4 a0 = {0.f, 0.f, 0.f, 0.f}, a1 = {0.f, 0.f, 0.f, 0.f};
    int i = 0;
    for (; i + 8 <= degp; i += 8) {
        unsigned off[4]; float av[4]; uint4 u[4];
#pragma unroll
        for (int k = 0; k < 4; ++k) {
            int e = i + 2 * k + half;
            off[k] = soff[w][e] + choff;
            av[k] = sex[w][e * 4 + h];
        }
#pragma unroll
        for (int k = 0; k < 4; ++k) u[k] = *(const uint4*)(hb + off[k]);
#pragma unroll
        for (int k = 0; k < 4; ++k) {
            a0.x += av[k] * bf_lo(u[k].x); a0.y += av[k] * bf_hi(u[k].x);
            a0.z += av[k] * bf_lo(u[k].y); a0.w += av[k] * bf_hi(u[k].y);
            a1.x += av[k] * bf_lo(u[k].z); a1.y += av[k] * bf_hi(u[k].z);
            a1.z += av[k] * bf_lo(u[k].w); a1.w += av[k] * bf_hi(u[k].w);
        }
    }
    for (; i < degp; i += 2) {
        int e = i + half;
        unsigned off = soff[w][e] + choff;
        float av = sex[w][e * 4 + h];
        uint4 u = *(const uint4*)(hb + off);
        a0.x += av * bf_lo(u.x); a0.y += av * bf_hi(u.x);
        a0.z += av * bf_lo(u.y); a0.w += av * bf_hi(u.y);
        a1.x += av * bf_lo(u.z); a1.y += av * bf_hi(u.z);
        a1.z += av * bf_lo(u.w); a1.w += av * bf_hi(u.w);
    }
    // combine the even/odd-edge half-wave partials
    a0.x += __shfl_xor(a0.x, 32); a0.y += __shfl_xor(a0.y, 32);
    a0.z += __shfl_xor(a0.z, 32); a0.w += __shfl_xor(a0.w, 32);
    a1.x += __shfl_xor(a1.x, 32); a1.y += __shfl_xor(a1.y, 32);
    a1.z += __shfl_xor(a1.z, 32); a1.w += __shfl_xor(a1.w, 32);

    float4 bb0 = *(const float4*)(b + ch),  bb1 = *(const float4*)(b + ch + 4);
    float4 gg0 = *(const float4*)(g + ch),  gg1 = *(const float4*)(g + ch + 4);
    float4 ee0 = *(const float4*)(be + ch), ee1 = *(const float4*)(be + ch + 4);
    float4 mm0 = *(const float4*)(rm + ch), mm1 = *(const float4*)(rm + ch + 4);
    float4 vv0 = *(const float4*)(rv + ch), vv1 = *(const float4*)(rv + ch + 4);
    float o0 = (a0.x * rden + bb0.x - mm0.x) * rsqrtf(vv0.x + BN_EPS) * gg0.x + ee0.x;
    float o1 = (a0.y * rden + bb0.y - mm0.y) * rsqrtf(vv0.y + BN_EPS) * gg0.y + ee0.y;
    float o2 = (a0.z * rden + bb0.z - mm0.z) * rsqrtf(vv0.z + BN_EPS) * gg0.z + ee0.z;
    float o3 = (a0.w * rden + bb0.w - mm0.w) * rsqrtf(vv0.w + BN_EPS) * gg0.w + ee0.w;
    float o4 = (a1.x * rden + bb1.x - mm1.x) * rsqrtf(vv1.x + BN_EPS) * gg1.x + ee1.x;
    float o5 = (a1.y * rden + bb1.y - mm1.y) * rsqrtf(vv1.y + BN_EPS) * gg1.y + ee1.y;
    float o6 = (a1.z * rden + bb1.z - mm1.z) * rsqrtf(vv1.z + BN_EPS) * gg1.z + ee1.z;
    float o7 = (a1.w * rden + bb1.w - mm1.w) * rsqrtf(vv1.w + BN_EPS) * gg1.w + ee1.w;
    o0 = o0 > 0.f ? o0 : expm1f(o0); o1 = o1 > 0.f ? o1 : expm1f(o1);
    o2 = o2 > 0.f ? o2 : expm1f(o2); o3 = o3 > 0.f ? o3 : expm1f(o3);
    o4 = o4 > 0.f ? o4 : expm1f(o4); o5 = o5 > 0.f ? o5 : expm1f(o5);
    o6 = o6 > 0.f ? o6 : expm1f(o6); o7 = o7 > 0.f ? o7 : expm1f(o7);
    if (half == 0) {
        u32x4 st = { packbf(o0, o1), packbf(o2, o3), packbf(o4, o5), packbf(o6, o7) };
        __builtin_nontemporal_store(st, (u32x4*)(out1 + (size_t)n * 256 + ch));
    }
}

// ------- Layer 2 fused + per-block pooled epilogue (no out2 materialization) ----
// Per-block LDS reduce of the 4 nodes' 128-ch vectors (batch sorted -> <=2 graph
// runs per block), then 128 atomics/block into 16 contention-split pool buckets:
// ~644K atomics over 32768 addresses (~20/address) — same density as the proven
// R8 pool. Saves out2 write+read (10MB) and one dispatch.
__global__ __launch_bounds__(256) void fused2_kernel(const unsigned short* __restrict__ ell,
                                                     const int* __restrict__ cnt,
                                                     const float* __restrict__ ssrc,
                                                     const float* __restrict__ sdst,
                                                     const __hip_bfloat16* __restrict__ h2,
                                                     const float* __restrict__ b,
                                                     const float* __restrict__ g,
                                                     const float* __restrict__ be,
                                                     const float* __restrict__ rm,
                                                     const float* __restrict__ rv,
                                                     const int* __restrict__ batch,
                                                     float* __restrict__ pool,
                                                     int N) {
    __shared__ float sex[4][ELLW];
    __shared__ unsigned soff[4][ELLW];       // per-edge h2 row byte offset (s*256)
    __shared__ float pacc[4][128];           // per-node pooled channel vec
    __shared__ int pg[4];                    // per-node graph id (-1 = inactive)
    const int w = threadIdx.x >> 6;
    const int lane = threadIdx.x & 63;
    const int n0 = blockIdx.x * 4 + w;
    const bool act = (n0 < N);
    const int n = act ? n0 : N - 1;
    if (lane == 0) pg[w] = act ? batch[n] : -1;
    const int degn = min(cnt[n], ELLW);
    const unsigned short* __restrict__ row = ell + (size_t)n * ELLW;
    const float sd = sdst[n];

    float den = 0.f;
    for (int i = lane; i < degn; i += 64) {
        int s = row[i];
        float e = eexp(lk(ssrc[s] + sd));
        sex[w][i] = e;
        soff[w][i] = (unsigned)s << 8;
        den += e;
    }
    if (lane == 0 && (degn & 1)) { sex[w][degn] = 0.f; soff[w][degn] = 0; }
#pragma unroll
    for (int o = 32; o; o >>= 1) den += __shfl_xor(den, o);
    const float rden = 1.f / (den + 1e-16f);

    const int half = lane >> 5;
    const int l32 = lane & 31;
    const int ch = l32 * 4;                  // 4 channels per lane
    const unsigned choff = (unsigned)(l32 * 8);
    const unsigned char* __restrict__ hb = (const unsigned char*)h2;
    const int degp = (degn + 1) & ~1;

    f32x4 acc = {0.f, 0.f, 0.f, 0.f};
    int i = 0;
    for (; i + 8 <= degp; i += 8) {
        unsigned off[4]; float av[4]; uint2 u[4];
#pragma unroll
        for (int k = 0; k < 4; ++k) {
            int e = i + 2 * k + half;
            off[k] = soff[w][e] + choff;
            av[k] = sex[w][e];
        }
#pragma unroll
        for (int k = 0; k < 4; ++k) u[k] = *(const uint2*)(hb + off[k]);
#pragma unroll
        for (int k = 0; k < 4; ++k) {
            acc.x += av[k] * bf_lo(u[k].x); acc.y += av[k] * bf_hi(u[k].x);
            acc.z += av[k] * bf_lo(u[k].y); acc.w += av[k] * bf_hi(u[k].y);
        }
    }
    for (; i < degp; i += 2) {
        int e = i + half;
        unsigned off = soff[w][e] + choff;
        float av = sex[w][e];
        uint2 u = *(const uint2*)(hb + off);
        acc.x += av * bf_lo(u.x); acc.y += av * bf_hi(u.x);
        acc.z += av * bf_lo(u.y); acc.w += av * bf_hi(u.y);
    }
    acc.x += __shfl_xor(acc.x, 32); acc.y += __shfl_xor(acc.y, 32);
    acc.z += __shfl_xor(acc.z, 32); acc.w += __shfl_xor(acc.w, 32);

    if (half == 0) {
        float4 bb = *(const float4*)(b + ch), gg = *(const float4*)(g + ch);
        float4 ee = *(const float4*)(be + ch), mm = *(const float4*)(rm + ch);
        float4 vv = *(const float4*)(rv + ch);
        pacc[w][ch + 0] = (acc.x * rden + bb.x - mm.x) * rsqrtf(vv.x + BN_EPS) * gg.x + ee.x;
        pacc[w][ch + 1] = (acc.y * rden + bb.y - mm.y) * rsqrtf(vv.y + BN_EPS) * gg.y + ee.y;
        pacc[w][ch + 2] = (acc.z * rden + bb.z - mm.z) * rsqrtf(vv.z + BN_EPS) * gg.z + ee.z;
        pacc[w][ch + 3] = (acc.w * rden + bb.w - mm.w) * rsqrtf(vv.w + BN_EPS) * gg.w + ee.w;
    }
    __syncthreads();
    if (w == 0 && half == 0) {
        float* __restrict__ pb = pool + (size_t)(blockIdx.x & (NPOOL - 1)) * 2048;
        float s0 = 0.f, s1 = 0.f, s2 = 0.f, s3 = 0.f;
        int curg = -1;
#pragma unroll
        for (int k = 0; k < 4; ++k) {
            int gk = pg[k];
            if (gk < 0) continue;
            if (gk != curg) {
                if (curg >= 0) {
                    float* pp = pb + (size_t)curg * 128 + ch;
                    atomAddF(pp + 0, s0); atomAddF(pp + 1, s1);
                    atomAddF(pp + 2, s2); atomAddF(pp + 3, s3);
                }
                curg = gk; s0 = s1 = s2 = s3 = 0.f;
            }
            s0 += pacc[k][ch + 0]; s1 += pacc[k][ch + 1];
            s2 += pacc[k][ch + 2]; s3 += pacc[k][ch + 3];
        }
        if (curg >= 0) {
            float* pp = pb + (size_t)curg * 128 + ch;
            atomAddF(pp + 0, s0); atomAddF(pp + 1, s1);
            atomAddF(pp + 2, s2); atomAddF(pp + 3, s3);
        }
    }
}

__device__ __forceinline__ int lowerBound(const int* __restrict__ a, int n, int v) {
    int lo = 0, hi = n;
    while (lo < hi) {
        int mid = (lo + hi) >> 1;
        if (a[mid] < v) lo = mid + 1; else hi = mid;
    }
    return lo;
}

__global__ __launch_bounds__(256) void final_kernel(const float* __restrict__ pool,
                                                    const int* __restrict__ batch,
                                                    float* __restrict__ out, int N) {
    int i = blockIdx.x * blockDim.x + threadIdx.x;  // 0..2047
    int g = i >> 7;
    int c = lowerBound(batch, N, g + 1) - lowerBound(batch, N, g);
    float s = 0.f;
#pragma unroll
    for (int k = 0; k < NPOOL; ++k) s += pool[(size_t)k * 2048 + i];
    out[i] = s / fmaxf((float)c, 1.f);
}

extern "C" void kernel_launch(void* const* d_in, const int* in_sizes, int n_in,
                              void* d_out, int out_size, void* d_ws, size_t ws_size,
                              hipStream_t stream) {
    const float* x    = (const float*)d_in[0];
    const int* ei     = (const int*)d_in[1];
    const int* batch  = (const int*)d_in[2];
    const float* W1   = (const float*)d_in[3];
    const float* as1  = (const float*)d_in[4];
    const float* ad1  = (const float*)d_in[5];
    const float* b1   = (const float*)d_in[6];
    const float* g1   = (const float*)d_in[7];
    const float* be1  = (const float*)d_in[8];
    const float* rm1  = (const float*)d_in[9];
    const float* rv1  = (const float*)d_in[10];
    const float* W2   = (const float*)d_in[11];
    const float* as2  = (const float*)d_in[12];
    const float* ad2  = (const float*)d_in[13];
    const float* b2   = (const float*)d_in[14];
    const float* g2   = (const float*)d_in[15];
    const float* be2  = (const float*)d_in[16];
    const float* rm2  = (const float*)d_in[17];
    const float* rv2  = (const float*)d_in[18];
    float* out = (float*)d_out;

    const int N = in_sizes[0] / 128;   // 20000
    const int E = in_sizes[1] / 2;     // 640000
    const int Etot = E + N;
    const int* src = ei;
    const int* dst = ei + E;

    // workspace carve (256B-aligned)
    char* p = (char*)d_ws;
    auto alloc = [&](size_t bytes) { char* r = p; p += (bytes + 255) & ~(size_t)255; return r; };
    __hip_bfloat16* h1   = (__hip_bfloat16*)alloc((size_t)N * 256 * 2);
    __hip_bfloat16* out1 = (__hip_bfloat16*)alloc((size_t)N * 256 * 2);
    __hip_bfloat16* xbf  = (__hip_bfloat16*)alloc((size_t)N * 128 * 2);
    __hip_bfloat16* WT1  = (__hip_bfloat16*)alloc(256 * 128 * 2);
    __hip_bfloat16* WT2  = (__hip_bfloat16*)alloc(128 * 256 * 2);
    // zeroed region: scores (N*10) + pool (NPOOL*2048) + cnt (N) — zeroed by prep
    const int zwords     = N * 10 + NPOOL * 2048 + N;
    char* zbase          = alloc((size_t)zwords * 4);
    float* ssrc1         = (float*)zbase;                    // N*4
    float* sdst1         = ssrc1 + (size_t)N * 4;            // N*4
    float* ssrc2         = sdst1 + (size_t)N * 4;            // N
    float* sdst2         = ssrc2 + N;                        // N
    float* pool          = sdst2 + N;                        // NPOOL*2048
    int*   cnt           = (int*)(pool + NPOOL * 2048);      // N
    unsigned short* ell  = (unsigned short*)alloc((size_t)N * ELLW * 2);
    __hip_bfloat16* h2   = h1;   // alias (h1 dead after fused1)

    // ---- prep (zero + casts + transposes) ----
    const int n4 = N * 128 / 4;
    const int ptot = n4 + 2 * 128 * 256 + zwords;
    prep_kernel<<<(ptot + 255) / 256, 256, 0, stream>>>(x, W1, W2, xbf, WT1, WT2,
                                                        (int*)zbase, zwords, n4);

    // ---- scatter ∥ gemm1 (independent; both depend only on prep) ----
    const int nbg1 = 4 * ((N + 63) / 64);   // 1252 gemm blocks
    sg1_kernel<<<nbg1 + 2048, 256, 0, stream>>>(xbf, WT1, h1, as1, ad1, ssrc1, sdst1,
                                                N, nbg1, src, dst, cnt, ell, N, E, Etot);

    // ---- layer 1 fused ----
    fused1_kernel<<<(N + 3) / 4, 256, 0, stream>>>(ell, cnt, ssrc1, sdst1, h1,
                                                   b1, g1, be1, rm1, rv1, out1, N);
    // ---- layer 2 ----
    gemm_score_kernel<<<dim3(128 / 64, (N + 63) / 64), 256, 0, stream>>>(
        out1, WT2, h2, as2, ad2, ssrc2, sdst2, N, 128, 256, 1);
    fused2_kernel<<<(N + 3) / 4, 256, 0, stream>>>(ell, cnt, ssrc2, sdst2, h2,
                                                   b2, g2, be2, rm2, rv2, batch, pool, N);

    // ---- final (pool fused into fused2 via per-block reduction) ----
    final_kernel<<<8, 256, 0, stream>>>(pool, batch, out, N);
}

// Round 14
// 225.916 us; speedup vs baseline: 1.0428x; 1.0428x over previous
//
#include <hip/hip_runtime.h>
#include <hip/hip_bf16.h>
#include <math.h>

#define NEG_SLOPE 0.2f
#define BN_EPS 1e-5f
#define ELLW 80          // ELL row width; deg = Poisson(32)+1, max over 20k nodes ~57; P(>80)~4e-13
#define SCLAMP 60.0f     // exp-arg clamp: scores analytically << 60; inf-guard only
#define LDP 68           // gemm LDS row stride in elements (136B)
#define NPOOL 16         // pool contention-splitting buckets

typedef __attribute__((ext_vector_type(8))) short bf16x8;
typedef __attribute__((ext_vector_type(4))) float f32x4;
typedef __attribute__((ext_vector_type(4))) unsigned u32x4;
typedef __attribute__((ext_vector_type(2))) unsigned u32x2;

__device__ __forceinline__ void atomAddF(float* p, float v) { unsafeAtomicAdd(p, v); }
__device__ __forceinline__ float bf_lo(unsigned u) { return __uint_as_float(u << 16); }
__device__ __forceinline__ float bf_hi(unsigned u) { return __uint_as_float(u & 0xffff0000u); }
__device__ __forceinline__ float lk(float x) { return x > 0.f ? x : NEG_SLOPE * x; }
__device__ __forceinline__ float eexp(float x) { return __expf(fminf(x, SCLAMP)); }
__device__ __forceinline__ unsigned packbf(float lo, float hi) {
    return (unsigned)__bfloat16_as_ushort(__float2bfloat16(lo)) |
           ((unsigned)__bfloat16_as_ushort(__float2bfloat16(hi)) << 16);
}

// ---- prep: zero scratch + cast x -> bf16 + transpose W1/W2 -> bf16 -------------
__global__ __launch_bounds__(256) void prep_kernel(const float* __restrict__ x,
                                                   const float* __restrict__ W1,
                                                   const float* __restrict__ W2,
                                                   __hip_bfloat16* __restrict__ xbf,
                                                   __hip_bfloat16* __restrict__ WT1,
                                                   __hip_bfloat16* __restrict__ WT2,
                                                   int* __restrict__ zb, int zwords,
                                                   int n4) {
    int i = blockIdx.x * blockDim.x + threadIdx.x;
    if (i < n4) {
        float4 v = ((const float4*)x)[i];
        ushort4 st;
        st.x = __bfloat16_as_ushort(__float2bfloat16(v.x));
        st.y = __bfloat16_as_ushort(__float2bfloat16(v.y));
        st.z = __bfloat16_as_ushort(__float2bfloat16(v.z));
        st.w = __bfloat16_as_ushort(__float2bfloat16(v.w));
        *(ushort4*)(xbf + (size_t)i * 4) = st;
        return;
    }
    int j = i - n4;
    if (j < 128 * 256) {          // W1 [128,256] -> WT1 [256,128]
        int k = j >> 8, n = j & 255;
        WT1[(size_t)n * 128 + k] = __float2bfloat16(W1[j]);
        return;
    }
    j -= 128 * 256;
    if (j < 256 * 128) {          // W2 [256,128] -> WT2 [128,256]
        int k = j >> 7, n = j & 127;
        WT2[(size_t)n * 256 + k] = __float2bfloat16(W2[j]);
        return;
    }
    j -= 256 * 128;
    if (j < zwords) zb[j] = 0;
}

// ------ MFMA GEMM body, LDS-staged, row-major C + score epilogue ------
__device__ __forceinline__ void gemm_body(const __hip_bfloat16* __restrict__ A,
                                          const __hip_bfloat16* __restrict__ BT,
                                          __hip_bfloat16* __restrict__ C,
                                          const float* __restrict__ asrc,
                                          const float* __restrict__ adst,
                                          float* __restrict__ ssrc,
                                          float* __restrict__ sdst,
                                          int M, int N, int K, int heads,
                                          int bx, int by) {
    __shared__ __hip_bfloat16 As[64 * LDP];
    __shared__ __hip_bfloat16 Bs[64 * LDP];
    const int tid = threadIdx.x;
    const int w = tid >> 6;
    const int lane = tid & 63;
    const int q = lane >> 4;
    const int r16 = lane & 15;
    const int bm = by * 64;
    const int bn = bx * 64;
    const int lrow = tid >> 3;
    const int lseg = tid & 7;
    f32x4 acc[4] = {};

    for (int k0 = 0; k0 < K; k0 += 64) {
#pragma unroll
        for (int half = 0; half < 2; ++half) {
            int row = lrow + half * 32;
            int ga = min(bm + row, M - 1);
            *(bf16x8*)(&As[row * LDP + lseg * 8]) =
                *(const bf16x8*)(A + (size_t)ga * K + k0 + lseg * 8);
            *(bf16x8*)(&Bs[row * LDP + lseg * 8]) =
                *(const bf16x8*)(BT + (size_t)(bn + row) * K + k0 + lseg * 8);
        }
        __syncthreads();
#pragma unroll
        for (int kk = 0; kk < 64; kk += 32) {
            bf16x8 a = *(const bf16x8*)(&As[(w * 16 + r16) * LDP + kk + q * 8]);
#pragma unroll
            for (int t = 0; t < 4; ++t) {
                bf16x8 b = *(const bf16x8*)(&Bs[(t * 16 + r16) * LDP + kk + q * 8]);
                acc[t] = __builtin_amdgcn_mfma_f32_16x16x32_bf16(a, b, acc[t], 0, 0, 0);
            }
        }
        __syncthreads();
    }
#pragma unroll
    for (int t = 0; t < 4; ++t)
#pragma unroll
        for (int r = 0; r < 4; ++r) {
            int row = bm + w * 16 + q * 4 + r;
            if (row < M)
                C[(size_t)row * N + bn + t * 16 + r16] = __float2bfloat16(acc[t][r]);
        }
    if (heads) {
        const int h = (heads == 4) ? bx : 0;
        float asv[4], adv[4];
#pragma unroll
        for (int t = 0; t < 4; ++t) {
            int col = bn + t * 16 + r16;
            asv[t] = asrc[col]; adv[t] = adst[col];
        }
#pragma unroll
        for (int r = 0; r < 4; ++r) {
            int row = bm + w * 16 + q * 4 + r;
            float ss = 0.f, sd = 0.f;
#pragma unroll
            for (int t = 0; t < 4; ++t) { ss += acc[t][r] * asv[t]; sd += acc[t][r] * adv[t]; }
#pragma unroll
            for (int mask = 1; mask <= 8; mask <<= 1) {
                ss += __shfl_xor(ss, mask);
                sd += __shfl_xor(sd, mask);
            }
            if (r16 == 0 && row < M) {
                atomAddF(&ssrc[(size_t)row * heads + h], ss);
                atomAddF(&sdst[(size_t)row * heads + h], sd);
            }
        }
    }
}

// ---- merged dispatch: blocks [0,nbg) do gemm1, the rest do the ELL scatter -----
__global__ __launch_bounds__(256) void sg1_kernel(const __hip_bfloat16* __restrict__ A,
                                                  const __hip_bfloat16* __restrict__ BT,
                                                  __hip_bfloat16* __restrict__ C,
                                                  const float* __restrict__ asrc,
                                                  const float* __restrict__ adst,
                                                  float* __restrict__ ssrc,
                                                  float* __restrict__ sdst,
                                                  int M, int nbg,
                                                  const int* __restrict__ src,
                                                  const int* __restrict__ dst,
                                                  int* __restrict__ cnt,
                                                  unsigned short* __restrict__ ell,
                                                  int N, int E, int Etot) {
    const int gb = blockIdx.x;
    if (gb < nbg) {
        gemm_body(A, BT, C, asrc, adst, ssrc, sdst, M, 256, 128, 4, gb & 3, gb >> 2);
        return;
    }
    // ---- scatter, XCD-partitioned by dst chunk (absolute blockIdx -> XCD) ----
    const int xcd = gb & 7;
    const int sb = gb - nbg;
    const int slice = sb >> 3;
    const int nslices = (gridDim.x - nbg) >> 3;
    const int d0 = (int)((long)xcd * N / 8);
    const int d1 = (int)((long)(xcd + 1) * N / 8);
    for (int e = slice * 256 + threadIdx.x; e < Etot; e += nslices * 256) {
        int d = (e < E) ? dst[e] : e - E;
        if (d < d0 || d >= d1) continue;
        int s = (e < E) ? src[e] : d;
        int pos = atomicAdd(cnt + d, 1);
        if (pos < ELLW) ell[(size_t)d * ELLW + pos] = (unsigned short)s;
    }
}

// ---- standalone gemm (layer 2) ----
__global__ __launch_bounds__(256) void gemm_score_kernel(const __hip_bfloat16* __restrict__ A,
                                                         const __hip_bfloat16* __restrict__ BT,
                                                         __hip_bfloat16* __restrict__ C,
                                                         const float* __restrict__ asrc,
                                                         const float* __restrict__ adst,
                                                         float* __restrict__ ssrc,
                                                         float* __restrict__ sdst,
                                                         int M, int N, int K, int heads) {
    gemm_body(A, BT, C, asrc, adst, ssrc, sdst, M, N, K, heads, blockIdx.x, blockIdx.y);
}

// ---------------- Layer 1 fused (v2, 8-deep — empirical best) -------------------
__global__ __launch_bounds__(256) void fused1_kernel(const unsigned short* __restrict__ ell,
                                                     const int* __restrict__ cnt,
                                                     const float* __restrict__ ssrc,
                                                     const float* __restrict__ sdst,
                                                     const __hip_bfloat16* __restrict__ h1,
                                                     const float* __restrict__ b,
                                                     const float* __restrict__ g,
                                                     const float* __restrict__ be,
                                                     const float* __restrict__ rm,
                                                     const float* __restrict__ rv,
                                                     __hip_bfloat16* __restrict__ out1,
                                                     int N) {
    __shared__ float sex[4][ELLW * 4];       // per-edge exp weights (4 heads)
    __shared__ unsigned soff[4][ELLW];       // per-edge h1 row byte offset (s*512)
    const int w = threadIdx.x >> 6;
    const int lane = threadIdx.x & 63;
    const int n = blockIdx.x * 4 + w;
    if (n >= N) return;
    const int degn = min(cnt[n], ELLW);
    const unsigned short* __restrict__ row = ell + (size_t)n * ELLW;
    const float4 sd4 = *(const float4*)(sdst + (size_t)n * 4);

    float4 d4 = {0.f, 0.f, 0.f, 0.f};
    for (int i = lane; i < degn; i += 64) {
        int s = row[i];
        float4 sc = *(const float4*)(ssrc + (size_t)s * 4);
        float4 e4;
        e4.x = eexp(lk(sc.x + sd4.x)); e4.y = eexp(lk(sc.y + sd4.y));
        e4.z = eexp(lk(sc.z + sd4.z)); e4.w = eexp(lk(sc.w + sd4.w));
        *(float4*)(&sex[w][i * 4]) = e4;
        soff[w][i] = (unsigned)s << 9;
        d4.x += e4.x; d4.y += e4.y; d4.z += e4.z; d4.w += e4.w;
    }
    if (lane == 0 && (degn & 1)) {           // pad odd degree with a zero edge
        float4 z = {0.f, 0.f, 0.f, 0.f};
        *(float4*)(&sex[w][degn * 4]) = z;
        soff[w][degn] = 0;
    }
#pragma unroll
    for (int o = 32; o; o >>= 1) {
        d4.x += __shfl_xor(d4.x, o); d4.y += __shfl_xor(d4.y, o);
        d4.z += __shfl_xor(d4.z, o); d4.w += __shfl_xor(d4.w, o);
    }

    const int half = lane >> 5;              // which edge of the pair
    const int l32 = lane & 31;
    const int ch = l32 * 8;                  // 8 channels per lane
    const int h = l32 >> 3;                  // head = ch/64
    const unsigned choff = (unsigned)(l32 * 16);  // ch*2 bytes
    const float denh = h == 0 ? d4.x : h == 1 ? d4.y : h == 2 ? d4.z : d4.w;
    const float rden = 1.f / (denh + 1e-16f);
    const unsigned char* __restrict__ hb = (const unsigned char*)h1;
    const int degp = (degn + 1) & ~1;

    f32x4 a0 = {0.f, 0.f, 0.f, 0.f}, a1 = {0.f, 0.f, 0.f, 0.f};
    int i = 0;
    for (; i + 8 <= degp; i += 8) {
        unsigned off[4]; float av[4]; uint4 u[4];
#pragma unroll
        for (int k = 0; k < 4; ++k) {
            int e = i + 2 * k + half;
            off[k] = soff[w][e] + choff;
            av[k] = sex[w][e * 4 + h];
        }
#pragma unroll
        for (int k = 0; k < 4; ++k) u[k] = *(const uint4*)(hb + off[k]);
#pragma unroll
        for (int k = 0; k < 4; ++k) {
            a0.x += av[k] * bf_lo(u[k].x); a0.y += av[k] * bf_hi(u[k].x);
            a0.z += av[k] * bf_lo(u[k].y); a0.w += av[k] * bf_hi(u[k].y);
            a1.x += av[k] * bf_lo(u[k].z); a1.y += av[k] * bf_hi(u[k].z);
            a1.z += av[k] * bf_lo(u[k].w); a1.w += av[k] * bf_hi(u[k].w);
        }
    }
    for (; i < degp; i += 2) {
        int e = i + half;
        unsigned off = soff[w][e] + choff;
        float av = sex[w][e * 4 + h];
        uint4 u = *(const uint4*)(hb + off);
        a0.x += av * bf_lo(u.x); a0.y += av * bf_hi(u.x);
        a0.z += av * bf_lo(u.y); a0.w += av * bf_hi(u.y);
        a1.x += av * bf_lo(u.z); a1.y += av * bf_hi(u.z);
        a1.z += av * bf_lo(u.w); a1.w += av * bf_hi(u.w);
    }
    // combine the even/odd-edge half-wave partials
    a0.x += __shfl_xor(a0.x, 32); a0.y += __shfl_xor(a0.y, 32);
    a0.z += __shfl_xor(a0.z, 32); a0.w += __shfl_xor(a0.w, 32);
    a1.x += __shfl_xor(a1.x, 32); a1.y += __shfl_xor(a1.y, 32);
    a1.z += __shfl_xor(a1.z, 32); a1.w += __shfl_xor(a1.w, 32);

    float4 bb0 = *(const float4*)(b + ch),  bb1 = *(const float4*)(b + ch + 4);
    float4 gg0 = *(const float4*)(g + ch),  gg1 = *(const float4*)(g + ch + 4);
    float4 ee0 = *(const float4*)(be + ch), ee1 = *(const float4*)(be + ch + 4);
    float4 mm0 = *(const float4*)(rm + ch), mm1 = *(const float4*)(rm + ch + 4);
    float4 vv0 = *(const float4*)(rv + ch), vv1 = *(const float4*)(rv + ch + 4);
    float o0 = (a0.x * rden + bb0.x - mm0.x) * rsqrtf(vv0.x + BN_EPS) * gg0.x + ee0.x;
    float o1 = (a0.y * rden + bb0.y - mm0.y) * rsqrtf(vv0.y + BN_EPS) * gg0.y + ee0.y;
    float o2 = (a0.z * rden + bb0.z - mm0.z) * rsqrtf(vv0.z + BN_EPS) * gg0.z + ee0.z;
    float o3 = (a0.w * rden + bb0.w - mm0.w) * rsqrtf(vv0.w + BN_EPS) * gg0.w + ee0.w;
    float o4 = (a1.x * rden + bb1.x - mm1.x) * rsqrtf(vv1.x + BN_EPS) * gg1.x + ee1.x;
    float o5 = (a1.y * rden + bb1.y - mm1.y) * rsqrtf(vv1.y + BN_EPS) * gg1.y + ee1.y;
    float o6 = (a1.z * rden + bb1.z - mm1.z) * rsqrtf(vv1.z + BN_EPS) * gg1.z + ee1.z;
    float o7 = (a1.w * rden + bb1.w - mm1.w) * rsqrtf(vv1.w + BN_EPS) * gg1.w + ee1.w;
    o0 = o0 > 0.f ? o0 : expm1f(o0); o1 = o1 > 0.f ? o1 : expm1f(o1);
    o2 = o2 > 0.f ? o2 : expm1f(o2); o3 = o3 > 0.f ? o3 : expm1f(o3);
    o4 = o4 > 0.f ? o4 : expm1f(o4); o5 = o5 > 0.f ? o5 : expm1f(o5);
    o6 = o6 > 0.f ? o6 : expm1f(o6); o7 = o7 > 0.f ? o7 : expm1f(o7);
    if (half == 0) {
        u32x4 st = { packbf(o0, o1), packbf(o2, o3), packbf(o4, o5), packbf(o6, o7) };
        __builtin_nontemporal_store(st, (u32x4*)(out1 + (size_t)n * 256 + ch));
    }
}

// ---------------- Layer 2 fused (v2, 8-deep — empirical best) -------------------
__global__ __launch_bounds__(256) void fused2_kernel(const unsigned short* __restrict__ ell,
                                                     const int* __restrict__ cnt,
                                                     const float* __restrict__ ssrc,
                                                     const float* __restrict__ sdst,
                                                     const __hip_bfloat16* __restrict__ h2,
                                                     const float* __restrict__ b,
                                                     const float* __restrict__ g,
                                                     const float* __restrict__ be,
                                                     const float* __restrict__ rm,
                                                     const float* __restrict__ rv,
                                                     __hip_bfloat16* __restrict__ out2,
                                                     int N) {
    __shared__ float sex[4][ELLW];
    __shared__ unsigned soff[4][ELLW];       // per-edge h2 row byte offset (s*256)
    const int w = threadIdx.x >> 6;
    const int lane = threadIdx.x & 63;
    const int n = blockIdx.x * 4 + w;
    if (n >= N) return;
    const int degn = min(cnt[n], ELLW);
    const unsigned short* __restrict__ row = ell + (size_t)n * ELLW;
    const float sd = sdst[n];

    float den = 0.f;
    for (int i = lane; i < degn; i += 64) {
        int s = row[i];
        float e = eexp(lk(ssrc[s] + sd));
        sex[w][i] = e;
        soff[w][i] = (unsigned)s << 8;
        den += e;
    }
    if (lane == 0 && (degn & 1)) { sex[w][degn] = 0.f; soff[w][degn] = 0; }
#pragma unroll
    for (int o = 32; o; o >>= 1) den += __shfl_xor(den, o);
    const float rden = 1.f / (den + 1e-16f);

    const int half = lane >> 5;
    const int l32 = lane & 31;
    const int ch = l32 * 4;                  // 4 channels per lane
    const unsigned choff = (unsigned)(l32 * 8);
    const unsigned char* __restrict__ hb = (const unsigned char*)h2;
    const int degp = (degn + 1) & ~1;

    f32x4 acc = {0.f, 0.f, 0.f, 0.f};
    int i = 0;
    for (; i + 8 <= degp; i += 8) {
        unsigned off[4]; float av[4]; uint2 u[4];
#pragma unroll
        for (int k = 0; k < 4; ++k) {
            int e = i + 2 * k + half;
            off[k] = soff[w][e] + choff;
            av[k] = sex[w][e];
        }
#pragma unroll
        for (int k = 0; k < 4; ++k) u[k] = *(const uint2*)(hb + off[k]);
#pragma unroll
        for (int k = 0; k < 4; ++k) {
            acc.x += av[k] * bf_lo(u[k].x); acc.y += av[k] * bf_hi(u[k].x);
            acc.z += av[k] * bf_lo(u[k].y); acc.w += av[k] * bf_hi(u[k].y);
        }
    }
    for (; i < degp; i += 2) {
        int e = i + half;
        unsigned off = soff[w][e] + choff;
        float av = sex[w][e];
        uint2 u = *(const uint2*)(hb + off);
        acc.x += av * bf_lo(u.x); acc.y += av * bf_hi(u.x);
        acc.z += av * bf_lo(u.y); acc.w += av * bf_hi(u.y);
    }
    acc.x += __shfl_xor(acc.x, 32); acc.y += __shfl_xor(acc.y, 32);
    acc.z += __shfl_xor(acc.z, 32); acc.w += __shfl_xor(acc.w, 32);

    if (half == 0) {
        float4 bb = *(const float4*)(b + ch), gg = *(const float4*)(g + ch);
        float4 ee = *(const float4*)(be + ch), mm = *(const float4*)(rm + ch);
        float4 vv = *(const float4*)(rv + ch);
        float o0 = (acc.x * rden + bb.x - mm.x) * rsqrtf(vv.x + BN_EPS) * gg.x + ee.x;
        float o1 = (acc.y * rden + bb.y - mm.y) * rsqrtf(vv.y + BN_EPS) * gg.y + ee.y;
        float o2 = (acc.z * rden + bb.z - mm.z) * rsqrtf(vv.z + BN_EPS) * gg.z + ee.z;
        float o3 = (acc.w * rden + bb.w - mm.w) * rsqrtf(vv.w + BN_EPS) * gg.w + ee.w;
        u32x2 st = { packbf(o0, o1), packbf(o2, o3) };
        __builtin_nontemporal_store(st, (u32x2*)(out2 + (size_t)n * 128 + ch));
    }
}

// ---------------- pooling (bf16 input, 16-way contention-split) ----------------
__global__ __launch_bounds__(128) void pool_kernel(const __hip_bfloat16* __restrict__ out2,
                                                   const int* __restrict__ batch,
                                                   float* __restrict__ pool,
                                                   int N, int npb) {
    const int j = threadIdx.x;
    float* __restrict__ pb = pool + (size_t)(blockIdx.x & (NPOOL - 1)) * 2048;
    int n0 = blockIdx.x * npb;
    int n1 = min(n0 + npb, N);
    if (n0 >= n1) return;
    int curg = batch[n0];
    float acc = 0.f;
    for (int n = n0; n < n1; ++n) {
        int gr = batch[n];
        if (gr != curg) {
            atomAddF(pb + (size_t)curg * 128 + j, acc);
            acc = 0.f; curg = gr;
        }
        acc += __bfloat162float(out2[(size_t)n * 128 + j]);
    }
    atomAddF(pb + (size_t)curg * 128 + j, acc);
}

__device__ __forceinline__ int lowerBound(const int* __restrict__ a, int n, int v) {
    int lo = 0, hi = n;
    while (lo < hi) {
        int mid = (lo + hi) >> 1;
        if (a[mid] < v) lo = mid + 1; else hi = mid;
    }
    return lo;
}

__global__ __launch_bounds__(256) void final_kernel(const float* __restrict__ pool,
                                                    const int* __restrict__ batch,
                                                    float* __restrict__ out, int N) {
    int i = blockIdx.x * blockDim.x + threadIdx.x;  // 0..2047
    int g = i >> 7;
    int c = lowerBound(batch, N, g + 1) - lowerBound(batch, N, g);
    float s = 0.f;
#pragma unroll
    for (int k = 0; k < NPOOL; ++k) s += pool[(size_t)k * 2048 + i];
    out[i] = s / fmaxf((float)c, 1.f);
}

extern "C" void kernel_launch(void* const* d_in, const int* in_sizes, int n_in,
                              void* d_out, int out_size, void* d_ws, size_t ws_size,
                              hipStream_t stream) {
    const float* x    = (const float*)d_in[0];
    const int* ei     = (const int*)d_in[1];
    const int* batch  = (const int*)d_in[2];
    const float* W1   = (const float*)d_in[3];
    const float* as1  = (const float*)d_in[4];
    const float* ad1  = (const float*)d_in[5];
    const float* b1   = (const float*)d_in[6];
    const float* g1   = (const float*)d_in[7];
    const float* be1  = (const float*)d_in[8];
    const float* rm1  = (const float*)d_in[9];
    const float* rv1  = (const float*)d_in[10];
    const float* W2   = (const float*)d_in[11];
    const float* as2  = (const float*)d_in[12];
    const float* ad2  = (const float*)d_in[13];
    const float* b2   = (const float*)d_in[14];
    const float* g2   = (const float*)d_in[15];
    const float* be2  = (const float*)d_in[16];
    const float* rm2  = (const float*)d_in[17];
    const float* rv2  = (const float*)d_in[18];
    float* out = (float*)d_out;

    const int N = in_sizes[0] / 128;   // 20000
    const int E = in_sizes[1] / 2;     // 640000
    const int Etot = E + N;
    const int* src = ei;
    const int* dst = ei + E;

    // workspace carve (256B-aligned)
    char* p = (char*)d_ws;
    auto alloc = [&](size_t bytes) { char* r = p; p += (bytes + 255) & ~(size_t)255; return r; };
    __hip_bfloat16* h1   = (__hip_bfloat16*)alloc((size_t)N * 256 * 2);
    __hip_bfloat16* out1 = (__hip_bfloat16*)alloc((size_t)N * 256 * 2);
    __hip_bfloat16* out2 = (__hip_bfloat16*)alloc((size_t)N * 128 * 2);
    __hip_bfloat16* xbf  = (__hip_bfloat16*)alloc((size_t)N * 128 * 2);
    __hip_bfloat16* WT1  = (__hip_bfloat16*)alloc(256 * 128 * 2);
    __hip_bfloat16* WT2  = (__hip_bfloat16*)alloc(128 * 256 * 2);
    // zeroed region: scores (N*10) + pool (NPOOL*2048) + cnt (N) — zeroed by prep
    const int zwords     = N * 10 + NPOOL * 2048 + N;
    char* zbase          = alloc((size_t)zwords * 4);
    float* ssrc1         = (float*)zbase;                    // N*4
    float* sdst1         = ssrc1 + (size_t)N * 4;            // N*4
    float* ssrc2         = sdst1 + (size_t)N * 4;            // N
    float* sdst2         = ssrc2 + N;                        // N
    float* pool          = sdst2 + N;                        // NPOOL*2048
    int*   cnt           = (int*)(pool + NPOOL * 2048);      // N
    unsigned short* ell  = (unsigned short*)alloc((size_t)N * ELLW * 2);
    __hip_bfloat16* h2   = h1;   // alias (h1 dead after fused1)

    // ---- prep (zero + casts + transposes) ----
    const int n4 = N * 128 / 4;
    const int ptot = n4 + 2 * 128 * 256 + zwords;
    prep_kernel<<<(ptot + 255) / 256, 256, 0, stream>>>(x, W1, W2, xbf, WT1, WT2,
                                                        (int*)zbase, zwords, n4);

    // ---- scatter ∥ gemm1 (independent; both depend only on prep) ----
    const int nbg1 = 4 * ((N + 63) / 64);   // 1252 gemm blocks
    sg1_kernel<<<nbg1 + 2048, 256, 0, stream>>>(xbf, WT1, h1, as1, ad1, ssrc1, sdst1,
                                                N, nbg1, src, dst, cnt, ell, N, E, Etot);

    // ---- layer 1 fused ----
    fused1_kernel<<<(N + 3) / 4, 256, 0, stream>>>(ell, cnt, ssrc1, sdst1, h1,
                                                   b1, g1, be1, rm1, rv1, out1, N);
    // ---- layer 2 ----
    gemm_score_kernel<<<dim3(128 / 64, (N + 63) / 64), 256, 0, stream>>>(
        out1, WT2, h2, as2, ad2, ssrc2, sdst2, N, 128, 256, 1);
    fused2_kernel<<<(N + 3) / 4, 256, 0, stream>>>(ell, cnt, ssrc2, sdst2, h2,
                                                   b2, g2, be2, rm2, rv2, out2, N);

    // ---- pool + final ----
    pool_kernel<<<(N + 9) / 10, 128, 0, stream>>>(out2, batch, pool, N, 10);
    final_kernel<<<8, 256, 0, stream>>>(pool, batch, out, N);
}